// Round 9
// baseline (497.549 us; speedup 1.0000x reference)
//
#include <hip/hip_runtime.h>
#include <stdint.h>

#define D_IN 250
#define H_DIM 100
#define RPW 32            // rows per wave
#define NTHREADS 256      // 4 waves
#define BM (4*RPW)        // 128 rows per block

// ws layout: 588 fragments of 512 bf16 elems each.
// pass1 frag id = t*36 + ks*3 + g      (t 0..6, ks 0..11 [0-7 X, 8-11 Hs], g 0..2 [r,z,n])
// pass2 frag id = 252 + t*48 + ks*3+g  (ks 0..15 [0-7 X, 8-11 Hp, 12-15 HsN], g [z,r,hn])
#define P2_FRAG 252
#define TOTAL_E ((252 + 336) * 512)     // 301056 elems

#define NSLOT 6           // LDS ring slots (3 KB each)

typedef __bf16 bf16x8 __attribute__((ext_vector_type(8)));
typedef float f32x4 __attribute__((ext_vector_type(4)));

static __device__ __forceinline__ uint16_t f2bf(float f) {
  uint32_t u = __builtin_bit_cast(uint32_t, f);
  u = (u + 0x7FFFu + ((u >> 16) & 1u)) >> 16;
  return (uint16_t)u;
}
static __device__ __forceinline__ float bf2f(uint16_t h) {
  uint32_t u = ((uint32_t)h) << 16;
  return __builtin_bit_cast(float, u);
}
static __device__ __forceinline__ float sigmoidf_(float x) {
  return 1.0f / (1.0f + __expf(-x));
}
static __device__ __forceinline__ float tanhf_(float x) {
  return 2.0f / (1.0f + __expf(-2.0f * x)) - 1.0f;
}

// ---------------- weight prepack: fp32 -> bf16 B-fragment layout -------------
__global__ void prepack_kernel(const float* __restrict__ Wi, const float* __restrict__ Wh,
                               const float* __restrict__ W_z, const float* __restrict__ U_z,
                               const float* __restrict__ Us_z, const float* __restrict__ W_r,
                               const float* __restrict__ U_r, const float* __restrict__ Us_r,
                               const float* __restrict__ W_hn, const float* __restrict__ U_hn,
                               const float* __restrict__ Us_hn, const float* __restrict__ bi,
                               const float* __restrict__ bh, uint16_t* __restrict__ ws) {
  int idx = blockIdx.x * blockDim.x + threadIdx.x;
  if (idx >= TOTAL_E) return;
  int f = idx >> 9;
  int a = idx & 511;
  int lane = a >> 3, j = a & 7;
  int kloc = ((lane >> 4) << 3) + j;
  int cl = lane & 15;
  float val = 0.f;
  if (f < P2_FRAG) {
    int g = f % 3, ks = (f / 3) % 12, t = f / 36;
    int c = t * 16 + cl;
    if (c < H_DIM) {
      if (ks < 8) {
        int k = ks * 32 + kloc;
        if (k < D_IN)       val = Wi[(size_t)(g * H_DIM + c) * D_IN + k];
        else if (k == D_IN) val = bi[g * H_DIM + c];
      } else {
        int k = (ks - 8) * 32 + kloc;
        if (k < H_DIM)       val = Wh[(size_t)(g * H_DIM + c) * H_DIM + k];
        else if (k == H_DIM) val = bh[g * H_DIM + c];
      }
    }
  } else {
    int f2 = f - P2_FRAG;
    int g = f2 % 3, ks = (f2 / 3) % 16, t = f2 / 48;
    int c = t * 16 + cl;
    if (c < H_DIM) {
      if (ks < 8) {
        int k = ks * 32 + kloc;
        const float* W = g == 0 ? W_z : g == 1 ? W_r : W_hn;
        if (k < D_IN) val = W[(size_t)c * D_IN + k];
      } else if (ks < 12) {
        int k = (ks - 8) * 32 + kloc;
        const float* W = g == 0 ? U_z : g == 1 ? U_r : U_hn;
        if (k < H_DIM) val = W[(size_t)c * H_DIM + k];
      } else {
        int k = (ks - 12) * 32 + kloc;
        const float* W = g == 0 ? Us_z : g == 1 ? Us_r : Us_hn;
        if (k < H_DIM) val = W[(size_t)c * H_DIM + k];
      }
    }
  }
  ws[idx] = f2bf(val);
}

// ------------------------- A-fragment direct loaders -------------------------
static __device__ __forceinline__ bf16x8 xfrag(const float* __restrict__ xr, int ks, int q) {
  int c0 = ks * 32 + q * 8;
  bf16x8 a;
  if (c0 < 248) {
    #pragma unroll
    for (int i = 0; i < 4; ++i) {
      float2 f = *(const float2*)(xr + c0 + 2 * i);
      a[2 * i] = (__bf16)f.x; a[2 * i + 1] = (__bf16)f.y;
    }
  } else {                    // cols 248,249 valid; 250 = bias 1.0; rest 0
    float2 f = *(const float2*)(xr + 248);
    a[0] = (__bf16)f.x; a[1] = (__bf16)f.y; a[2] = (__bf16)1.0f;
    a[3] = (__bf16)0.0f; a[4] = (__bf16)0.0f; a[5] = (__bf16)0.0f;
    a[6] = (__bf16)0.0f; a[7] = (__bf16)0.0f;
  }
  return a;
}
static __device__ __forceinline__ bf16x8 hfrag(const float* __restrict__ hr, int ks, int q, float bias) {
  int c0 = ks * 32 + q * 8;
  bf16x8 a;
  #pragma unroll
  for (int i = 0; i < 8; ++i) a[i] = (__bf16)0.0f;
  if (c0 <= 88) {
    #pragma unroll
    for (int i = 0; i < 4; ++i) {
      float2 f = *(const float2*)(hr + c0 + 2 * i);
      a[2 * i] = (__bf16)f.x; a[2 * i + 1] = (__bf16)f.y;
    }
  } else if (c0 == 96) {      // cols 96..99 valid; 100 = bias; rest 0
    float2 f0 = *(const float2*)(hr + 96);
    float2 f1 = *(const float2*)(hr + 98);
    a[0] = (__bf16)f0.x; a[1] = (__bf16)f0.y; a[2] = (__bf16)f1.x; a[3] = (__bf16)f1.y;
    a[4] = (__bf16)bias;
  }
  return a;
}

#define MFMA(A, B, C) __builtin_amdgcn_mfma_f32_16x16x32_bf16((A), (B), (C), 0, 0, 0)

// --------------- block-shared B ring: global -> LDS DMA ----------------------
typedef const __attribute__((address_space(1))) unsigned int* gp1_t;
typedef __attribute__((address_space(3))) unsigned int* lp3_t;

static __device__ __forceinline__ void gload(const uint16_t* gsrc, uint16_t* ldst) {
  __builtin_amdgcn_global_load_lds((gp1_t)gsrc, (lp3_t)ldst, 16, 0, 0);
}
#define WAIT_VM2   asm volatile("s_waitcnt vmcnt(2)" ::: "memory")
#define WAIT_LGKM0 asm volatile("s_waitcnt lgkmcnt(0)" ::: "memory")
#define BAR        do { __builtin_amdgcn_s_barrier(); __builtin_amdgcn_sched_barrier(0); } while (0)

static __device__ __forceinline__ int adv(int s, int n) {
  s += n;
  return s >= NSLOT ? s - NSLOT : s;
}

// ---------------------------- fused GRU kernel -------------------------------
// nt-outer / K-inner; A in registers; B streamed through a BLOCK-SHARED 6-slot
// LDS ring: waves 0-2 each DMA one fragment per K-step at depth 4, all 4 waves
// consume. TWO K-steps per barrier (98 barriers total). 3 blocks/CU.
__global__ __launch_bounds__(NTHREADS, 3) void gru_fused(
    const float* __restrict__ x, const float* __restrict__ hp_g,
    const float* __restrict__ hs_g, const uint16_t* __restrict__ ws,
    float* __restrict__ out) {
  __shared__ __align__(16) uint16_t ldsT[4 * RPW * 128];   // 32 KB: Hs->HsNew, then Hp
  __shared__ __align__(16) uint16_t ring[NSLOT * 1536];    // 18 KB: 6 slots x 3 frags

  const int tid = threadIdx.x;
  const int lane = tid & 63, wid = tid >> 6;
  const int q = lane >> 4, cl = lane & 15;
  const int rowbase = blockIdx.x * BM + wid * RPW;
  uint16_t* lT = ldsT + wid * (RPW * 128);
  const uint16_t* wsl = ws + lane * 8;

  // ---- prologue: load ALL A fragments (xa, ha, pa) ----
  bf16x8 xa[2][8], ha[2][4], pa[2][4];
  #pragma unroll
  for (int h = 0; h < 2; ++h) {
    const float* xr = x + (size_t)(rowbase + h * 16 + cl) * D_IN;
    #pragma unroll
    for (int ks = 0; ks < 8; ++ks) xa[h][ks] = xfrag(xr, ks, q);
    const float* hr = hs_g + (size_t)(rowbase + h * 16 + cl) * H_DIM;
    #pragma unroll
    for (int ks = 0; ks < 4; ++ks) ha[h][ks] = hfrag(hr, ks, q, 1.0f);
    const float* pr = hp_g + (size_t)(rowbase + h * 16 + cl) * H_DIM;
    #pragma unroll
    for (int ks = 0; ks < 4; ++ks) pa[h][ks] = hfrag(pr, ks, q, 0.0f);
  }

  // stage Hs (bf16) into lT in the A-layout (swizzled); covers cols 0..127
  #pragma unroll
  for (int h = 0; h < 2; ++h) {
    int row = h * 16 + cl;
    #pragma unroll
    for (int ks = 0; ks < 4; ++ks) {
      int bo = row * 256 + (((ks * 64) + q * 16) ^ ((row & 7) << 4));
      *(bf16x8*)((char*)lT + bo) = ha[h][ks];
    }
  }

  // ring prologue: issue steps 0..3 (t=0: fid = s*3 + g) into slots 0..3
  if (wid < 3) {
    #pragma unroll
    for (int s = 0; s < 4; ++s)
      gload(wsl + (size_t)(s * 3 + wid) * 512, ring + s * 1536 + wid * 512);
    WAIT_VM2;                                  // slots 0,1 landed
  }
  BAR;

  int cslot = 0, islot = 4;

  // =========================== PASS 1 (GRU cell) ============================
  #pragma unroll 1
  for (int t = 0; t < 7; ++t) {
    f32x4 aR[2], aZ[2], aNi[2], aNh[2];
    #pragma unroll
    for (int h = 0; h < 2; ++h) { aR[h] = (f32x4)(0.f); aZ[h] = (f32x4)(0.f); aNi[h] = (f32x4)(0.f); aNh[h] = (f32x4)(0.f); }
    #pragma unroll
    for (int ks = 0; ks < 12; ks += 2) {
      int c0s = cslot, c1s = adv(cslot, 1);
      // ---- step ks: consume slot c0s ----
      const uint16_t* spa = ring + c0s * 1536 + lane * 8;
      bf16x8 a0 = *(const bf16x8*)(spa);
      bf16x8 a1 = *(const bf16x8*)(spa + 512);
      bf16x8 a2 = *(const bf16x8*)(spa + 1024);
      if (wid < 3) {
        int f1 = (ks + 4 < 12) ? (t * 36 + (ks + 4) * 3)
               : (t < 6 ? ((t + 1) * 36 + (ks - 8) * 3) : (P2_FRAG + (ks - 8) * 3));
        gload(wsl + (size_t)(f1 + wid) * 512, ring + islot * 1536 + wid * 512);
      }
      __builtin_amdgcn_s_setprio(1);
      #pragma unroll
      for (int h = 0; h < 2; ++h) {
        bf16x8 av = (ks < 8) ? xa[h][ks] : ha[h][ks - 8];
        aR[h] = MFMA(av, a0, aR[h]);
        aZ[h] = MFMA(av, a1, aZ[h]);
        if (ks < 8) aNi[h] = MFMA(av, a2, aNi[h]);
        else        aNh[h] = MFMA(av, a2, aNh[h]);
      }
      __builtin_amdgcn_s_setprio(0);
      // ---- step ks+1: consume slot c1s ----
      const uint16_t* spb = ring + c1s * 1536 + lane * 8;
      bf16x8 b0 = *(const bf16x8*)(spb);
      bf16x8 b1 = *(const bf16x8*)(spb + 512);
      bf16x8 b2 = *(const bf16x8*)(spb + 1024);
      if (wid < 3) {
        int f2_ = (ks + 5 < 12) ? (t * 36 + (ks + 5) * 3)
                : (t < 6 ? ((t + 1) * 36 + (ks - 7) * 3) : (P2_FRAG + (ks - 7) * 3));
        gload(wsl + (size_t)(f2_ + wid) * 512, ring + adv(islot, 1) * 1536 + wid * 512);
      }
      __builtin_amdgcn_s_setprio(1);
      #pragma unroll
      for (int h = 0; h < 2; ++h) {
        bf16x8 av = (ks + 1 < 8) ? xa[h][ks + 1] : ha[h][ks + 1 - 8];
        aR[h] = MFMA(av, b0, aR[h]);
        aZ[h] = MFMA(av, b1, aZ[h]);
        if (ks + 1 < 8) aNi[h] = MFMA(av, b2, aNi[h]);
        else            aNh[h] = MFMA(av, b2, aNh[h]);
      }
      __builtin_amdgcn_s_setprio(0);
      cslot = adv(cslot, 2); islot = adv(islot, 2);
      if (wid < 3) WAIT_VM2;                   // next 2 consume slots landed
      BAR;
    }
    // elementwise GRU cell -> HsNew written in place into lT (bf16)
    int c = t * 16 + cl;
    #pragma unroll
    for (int h = 0; h < 2; ++h) {
      #pragma unroll
      for (int r = 0; r < 4; ++r) {
        int row = h * 16 + q * 4 + r;
        int bo = row * 256 + ((c * 2) ^ ((row & 7) << 4));
        float hsp = bf2f(*(const uint16_t*)((const char*)lT + bo));
        float rr = sigmoidf_(aR[h][r]);
        float zz = sigmoidf_(aZ[h][r]);
        float nn = tanhf_(aNi[h][r] + rr * aNh[h][r]);
        float hsn = (1.f - zz) * nn + zz * hsp;
        *(uint16_t*)((char*)lT + bo) = f2bf(hsn);
      }
    }
  }

  // ---- boundary: HsNew frags out of lT, then stage Hp into lT (wave-private) ----
  bf16x8 na[2][4];
  #pragma unroll
  for (int h = 0; h < 2; ++h) {
    int row = h * 16 + cl;
    #pragma unroll
    for (int ks = 0; ks < 4; ++ks) {
      int bo = row * 256 + (((ks * 64) + q * 16) ^ ((row & 7) << 4));
      na[h][ks] = *(const bf16x8*)((const char*)lT + bo);
    }
  }
  WAIT_LGKM0;                                  // na in regs before overwrite
  #pragma unroll
  for (int h = 0; h < 2; ++h) {
    int row = h * 16 + cl;
    #pragma unroll
    for (int ks = 0; ks < 4; ++ks) {
      int bo = row * 256 + (((ks * 64) + q * 16) ^ ((row & 7) << 4));
      *(bf16x8*)((char*)lT + bo) = pa[h][ks];
    }
  }

  // =========================== PASS 2 (task head) ===========================
  #pragma unroll 1
  for (int t = 0; t < 7; ++t) {
    f32x4 aZ[2], aR[2], aNa[2], aNb[2];
    #pragma unroll
    for (int h = 0; h < 2; ++h) { aZ[h] = (f32x4)(0.f); aR[h] = (f32x4)(0.f); aNa[h] = (f32x4)(0.f); aNb[h] = (f32x4)(0.f); }
    #pragma unroll
    for (int ks = 0; ks < 16; ks += 2) {
      int c0s = cslot, c1s = adv(cslot, 1);
      // ---- step ks ----
      const uint16_t* spa = ring + c0s * 1536 + lane * 8;
      bf16x8 a0 = *(const bf16x8*)(spa);
      bf16x8 a1 = *(const bf16x8*)(spa + 512);
      bf16x8 a2 = *(const bf16x8*)(spa + 1024);
      if (wid < 3) {
        int f1 = (ks + 4 < 16) ? (P2_FRAG + t * 48 + (ks + 4) * 3)
               : (t < 6 ? (P2_FRAG + (t + 1) * 48 + (ks - 12) * 3) : (P2_FRAG + 6 * 48 + 45));
        gload(wsl + (size_t)(f1 + wid) * 512, ring + islot * 1536 + wid * 512);
      }
      __builtin_amdgcn_s_setprio(1);
      #pragma unroll
      for (int h = 0; h < 2; ++h) {
        bf16x8 av = (ks < 8) ? xa[h][ks] : (ks < 12) ? pa[h][ks - 8] : na[h][ks - 12];
        aZ[h] = MFMA(av, a0, aZ[h]);
        aR[h] = MFMA(av, a1, aR[h]);
        if (ks < 8)       aNa[h] = MFMA(av, a2, aNa[h]);
        else if (ks < 12) aNb[h] = MFMA(av, a2, aNb[h]);
        else              aNa[h] = MFMA(av, a2, aNa[h]);
      }
      __builtin_amdgcn_s_setprio(0);
      // ---- step ks+1 ----
      const uint16_t* spb = ring + c1s * 1536 + lane * 8;
      bf16x8 b0 = *(const bf16x8*)(spb);
      bf16x8 b1 = *(const bf16x8*)(spb + 512);
      bf16x8 b2 = *(const bf16x8*)(spb + 1024);
      if (wid < 3) {
        int f2_ = (ks + 5 < 16) ? (P2_FRAG + t * 48 + (ks + 5) * 3)
                : (t < 6 ? (P2_FRAG + (t + 1) * 48 + (ks - 11) * 3) : (P2_FRAG + 6 * 48 + 45));
        gload(wsl + (size_t)(f2_ + wid) * 512, ring + adv(islot, 1) * 1536 + wid * 512);
      }
      __builtin_amdgcn_s_setprio(1);
      #pragma unroll
      for (int h = 0; h < 2; ++h) {
        bf16x8 av = (ks + 1 < 8) ? xa[h][ks + 1] : (ks + 1 < 12) ? pa[h][ks + 1 - 8] : na[h][ks + 1 - 12];
        aZ[h] = MFMA(av, b0, aZ[h]);
        aR[h] = MFMA(av, b1, aR[h]);
        if (ks + 1 < 8)       aNa[h] = MFMA(av, b2, aNa[h]);
        else if (ks + 1 < 12) aNb[h] = MFMA(av, b2, aNb[h]);
        else                  aNa[h] = MFMA(av, b2, aNa[h]);
      }
      __builtin_amdgcn_s_setprio(0);
      cslot = adv(cslot, 2); islot = adv(islot, 2);
      if (wid < 3) WAIT_VM2;
      BAR;
    }
    // elementwise + store (hpv from lT)
    int c = t * 16 + cl;
    bool valid = c < H_DIM;
    #pragma unroll
    for (int h = 0; h < 2; ++h) {
      #pragma unroll
      for (int r = 0; r < 4; ++r) {
        int row = h * 16 + q * 4 + r;
        int bo = row * 256 + ((c * 2) ^ ((row & 7) << 4));
        float hpv = bf2f(*(const uint16_t*)((const char*)lT + bo));
        float z2 = sigmoidf_(aZ[h][r]);
        float r2 = sigmoidf_(aR[h][r]);
        float nm = tanhf_(aNa[h][r] + r2 * aNb[h][r]);
        float hnew = (1.f - z2) * nm + z2 * hpv;
        if (valid) out[(size_t)(rowbase + row) * H_DIM + c] = hnew;
      }
    }
  }
}

extern "C" void kernel_launch(void* const* d_in, const int* in_sizes, int n_in,
                              void* d_out, int out_size, void* d_ws, size_t ws_size,
                              hipStream_t stream) {
  const float* x    = (const float*)d_in[0];
  const float* h_p  = (const float*)d_in[1];
  const float* h_s  = (const float*)d_in[2];
  const float* Wi   = (const float*)d_in[3];
  const float* Wh   = (const float*)d_in[4];
  const float* bi   = (const float*)d_in[5];
  const float* bh   = (const float*)d_in[6];
  const float* W_z  = (const float*)d_in[7];
  const float* U_z  = (const float*)d_in[8];
  const float* Us_z = (const float*)d_in[9];
  const float* W_r  = (const float*)d_in[10];
  const float* U_r  = (const float*)d_in[11];
  const float* Us_r = (const float*)d_in[12];
  const float* W_hn = (const float*)d_in[13];
  const float* U_hn = (const float*)d_in[14];
  const float* Us_hn= (const float*)d_in[15];
  uint16_t* ws = (uint16_t*)d_ws;
  float* out = (float*)d_out;

  int rows = in_sizes[0] / D_IN;          // 262144
  prepack_kernel<<<(TOTAL_E + 255) / 256, 256, 0, stream>>>(
      Wi, Wh, W_z, U_z, Us_z, W_r, U_r, Us_r, W_hn, U_hn, Us_hn, bi, bh, ws);
  gru_fused<<<rows / BM, NTHREADS, 0, stream>>>(x, h_p, h_s, ws, out);
}

// Round 10
// 306.100 us; speedup vs baseline: 1.6254x; 1.6254x over previous
//
#include <hip/hip_runtime.h>
#include <stdint.h>

#define D_IN 250
#define H_DIM 100
#define RPW 32            // rows per wave
#define NTHREADS 256      // 4 waves
#define BM (4*RPW)        // 128 rows per block

// ws layout: 588 fragments of 512 bf16 elems each.
// pass1 frag id = t*36 + ks*3 + g      (t 0..6, ks 0..11 [0-7 X, 8-11 Hs], g 0..2 [r,z,n])
// pass2 frag id = 252 + t*48 + ks*3+g  (ks 0..15 [0-7 X, 8-11 Hp, 12-15 HsN], g [z,r,hn])
#define P2_FRAG 252
#define TOTAL_E ((252 + 336) * 512)     // 301056 elems

#define NSLOT 12          // LDS ring slots (3 KB each) = one pass1 revolution

typedef __bf16 bf16x8 __attribute__((ext_vector_type(8)));
typedef float f32x4 __attribute__((ext_vector_type(4)));

static __device__ __forceinline__ uint16_t f2bf(float f) {
  uint32_t u = __builtin_bit_cast(uint32_t, f);
  u = (u + 0x7FFFu + ((u >> 16) & 1u)) >> 16;
  return (uint16_t)u;
}
static __device__ __forceinline__ float bf2f(uint16_t h) {
  uint32_t u = ((uint32_t)h) << 16;
  return __builtin_bit_cast(float, u);
}
static __device__ __forceinline__ float sigmoidf_(float x) {
  return 1.0f / (1.0f + __expf(-x));
}
static __device__ __forceinline__ float tanhf_(float x) {
  return 2.0f / (1.0f + __expf(-2.0f * x)) - 1.0f;
}

// ---------------- weight prepack: fp32 -> bf16 B-fragment layout -------------
__global__ void prepack_kernel(const float* __restrict__ Wi, const float* __restrict__ Wh,
                               const float* __restrict__ W_z, const float* __restrict__ U_z,
                               const float* __restrict__ Us_z, const float* __restrict__ W_r,
                               const float* __restrict__ U_r, const float* __restrict__ Us_r,
                               const float* __restrict__ W_hn, const float* __restrict__ U_hn,
                               const float* __restrict__ Us_hn, const float* __restrict__ bi,
                               const float* __restrict__ bh, uint16_t* __restrict__ ws) {
  int idx = blockIdx.x * blockDim.x + threadIdx.x;
  if (idx >= TOTAL_E) return;
  int f = idx >> 9;
  int a = idx & 511;
  int lane = a >> 3, j = a & 7;
  int kloc = ((lane >> 4) << 3) + j;
  int cl = lane & 15;
  float val = 0.f;
  if (f < P2_FRAG) {
    int g = f % 3, ks = (f / 3) % 12, t = f / 36;
    int c = t * 16 + cl;
    if (c < H_DIM) {
      if (ks < 8) {
        int k = ks * 32 + kloc;
        if (k < D_IN)       val = Wi[(size_t)(g * H_DIM + c) * D_IN + k];
        else if (k == D_IN) val = bi[g * H_DIM + c];
      } else {
        int k = (ks - 8) * 32 + kloc;
        if (k < H_DIM)       val = Wh[(size_t)(g * H_DIM + c) * H_DIM + k];
        else if (k == H_DIM) val = bh[g * H_DIM + c];
      }
    }
  } else {
    int f2 = f - P2_FRAG;
    int g = f2 % 3, ks = (f2 / 3) % 16, t = f2 / 48;
    int c = t * 16 + cl;
    if (c < H_DIM) {
      if (ks < 8) {
        int k = ks * 32 + kloc;
        const float* W = g == 0 ? W_z : g == 1 ? W_r : W_hn;
        if (k < D_IN) val = W[(size_t)c * D_IN + k];
      } else if (ks < 12) {
        int k = (ks - 8) * 32 + kloc;
        const float* W = g == 0 ? U_z : g == 1 ? U_r : U_hn;
        if (k < H_DIM) val = W[(size_t)c * H_DIM + k];
      } else {
        int k = (ks - 12) * 32 + kloc;
        const float* W = g == 0 ? Us_z : g == 1 ? Us_r : Us_hn;
        if (k < H_DIM) val = W[(size_t)c * H_DIM + k];
      }
    }
  }
  ws[idx] = f2bf(val);
}

// ------------------------- A-fragment direct loaders -------------------------
static __device__ __forceinline__ bf16x8 xfrag(const float* __restrict__ xr, int ks, int q) {
  int c0 = ks * 32 + q * 8;
  bf16x8 a;
  if (c0 < 248) {
    #pragma unroll
    for (int i = 0; i < 4; ++i) {
      float2 f = *(const float2*)(xr + c0 + 2 * i);
      a[2 * i] = (__bf16)f.x; a[2 * i + 1] = (__bf16)f.y;
    }
  } else {                    // cols 248,249 valid; 250 = bias 1.0; rest 0
    float2 f = *(const float2*)(xr + 248);
    a[0] = (__bf16)f.x; a[1] = (__bf16)f.y; a[2] = (__bf16)1.0f;
    a[3] = (__bf16)0.0f; a[4] = (__bf16)0.0f; a[5] = (__bf16)0.0f;
    a[6] = (__bf16)0.0f; a[7] = (__bf16)0.0f;
  }
  return a;
}
static __device__ __forceinline__ bf16x8 hfrag(const float* __restrict__ hr, int ks, int q, float bias) {
  int c0 = ks * 32 + q * 8;
  bf16x8 a;
  #pragma unroll
  for (int i = 0; i < 8; ++i) a[i] = (__bf16)0.0f;
  if (c0 <= 88) {
    #pragma unroll
    for (int i = 0; i < 4; ++i) {
      float2 f = *(const float2*)(hr + c0 + 2 * i);
      a[2 * i] = (__bf16)f.x; a[2 * i + 1] = (__bf16)f.y;
    }
  } else if (c0 == 96) {      // cols 96..99 valid; 100 = bias; rest 0
    float2 f0 = *(const float2*)(hr + 96);
    float2 f1 = *(const float2*)(hr + 98);
    a[0] = (__bf16)f0.x; a[1] = (__bf16)f0.y; a[2] = (__bf16)f1.x; a[3] = (__bf16)f1.y;
    a[4] = (__bf16)bias;
  }
  return a;
}

#define MFMA(A, B, C) __builtin_amdgcn_mfma_f32_16x16x32_bf16((A), (B), (C), 0, 0, 0)

// --------------- block-shared B ring: global -> LDS DMA ----------------------
typedef const __attribute__((address_space(1))) unsigned int* gp1_t;
typedef __attribute__((address_space(3))) unsigned int* lp3_t;

static __device__ __forceinline__ void gload(const uint16_t* gsrc, uint16_t* ldst) {
  __builtin_amdgcn_global_load_lds((gp1_t)gsrc, (lp3_t)ldst, 16, 0, 0);
}
#define WAIT_VM3   asm volatile("s_waitcnt vmcnt(3)" ::: "memory")
#define WAIT_LGKM0 asm volatile("s_waitcnt lgkmcnt(0)" ::: "memory")
#define BAR        do { __builtin_amdgcn_s_barrier(); __builtin_amdgcn_sched_barrier(0); } while (0)

// ---------------------------- fused GRU kernel -------------------------------
// nt-outer / K-inner; A in registers; B streamed through a BLOCK-SHARED 12-slot
// LDS ring. Groups of 4 K-steps per barrier; ALL 4 waves issue (wave w DMAs the
// 3 fragments of step group+8+w). vmcnt(3) per wave + barrier = landing proof.
__global__ __launch_bounds__(NTHREADS, 2) void gru_fused(
    const float* __restrict__ x, const float* __restrict__ hp_g,
    const float* __restrict__ hs_g, const uint16_t* __restrict__ ws,
    float* __restrict__ out) {
  __shared__ __align__(16) uint16_t ldsT[4 * RPW * 128];   // 32 KB: Hs->HsNew, then Hp
  __shared__ __align__(16) uint16_t ring[NSLOT * 1536];    // 36 KB: 12 slots x 3 frags

  const int tid = threadIdx.x;
  const int lane = tid & 63, wid = tid >> 6;
  const int q = lane >> 4, cl = lane & 15;
  const int rowbase = blockIdx.x * BM + wid * RPW;
  uint16_t* lT = ldsT + wid * (RPW * 128);
  const uint16_t* wsl = ws + lane * 8;

  // ---- prologue: load ALL A fragments (xa, ha, pa) ----
  bf16x8 xa[2][8], ha[2][4], pa[2][4];
  #pragma unroll
  for (int h = 0; h < 2; ++h) {
    const float* xr = x + (size_t)(rowbase + h * 16 + cl) * D_IN;
    #pragma unroll
    for (int ks = 0; ks < 8; ++ks) xa[h][ks] = xfrag(xr, ks, q);
    const float* hr = hs_g + (size_t)(rowbase + h * 16 + cl) * H_DIM;
    #pragma unroll
    for (int ks = 0; ks < 4; ++ks) ha[h][ks] = hfrag(hr, ks, q, 1.0f);
    const float* pr = hp_g + (size_t)(rowbase + h * 16 + cl) * H_DIM;
    #pragma unroll
    for (int ks = 0; ks < 4; ++ks) pa[h][ks] = hfrag(pr, ks, q, 0.0f);
  }

  // stage Hs (bf16) into lT in the A-layout (swizzled); covers cols 0..127
  #pragma unroll
  for (int h = 0; h < 2; ++h) {
    int row = h * 16 + cl;
    #pragma unroll
    for (int ks = 0; ks < 4; ++ks) {
      int bo = row * 256 + (((ks * 64) + q * 16) ^ ((row & 7) << 4));
      *(bf16x8*)((char*)lT + bo) = ha[h][ks];
    }
  }

  // ring prologue: steps 0..7 (t=0 ks 0..7); wave w loads steps w and 4+w
  {
    int f0 = wid * 3;
    #pragma unroll
    for (int gg = 0; gg < 3; ++gg)
      gload(wsl + (size_t)(f0 + gg) * 512, ring + wid * 1536 + gg * 512);
    int f1 = (4 + wid) * 3;
    #pragma unroll
    for (int gg = 0; gg < 3; ++gg)
      gload(wsl + (size_t)(f1 + gg) * 512, ring + (4 + wid) * 1536 + gg * 512);
    WAIT_VM3;                                  // own step-w loads landed
  }
  BAR;                                          // union: steps 0..3 ready

  // =========================== PASS 1 (GRU cell) ============================
  // 12 steps per t = exactly one ring revolution -> slots are static (= ks).
  #pragma unroll 1
  for (int t = 0; t < 7; ++t) {
    f32x4 aR[2], aZ[2], aNi[2], aNh[2];
    #pragma unroll
    for (int h = 0; h < 2; ++h) { aR[h] = (f32x4)(0.f); aZ[h] = (f32x4)(0.f); aNi[h] = (f32x4)(0.f); aNh[h] = (f32x4)(0.f); }
    #pragma unroll
    for (int g = 0; g < 3; ++g) {
      // issue step (t*12 + 4g + 8 + wid): all 3 gates, one step per wave
      int islot = (g == 0) ? (8 + wid) : (g == 1) ? wid : (4 + wid);
      int fid;
      if (g == 0)      fid = t * 36 + (8 + wid) * 3;
      else if (g == 1) fid = (t < 6) ? ((t + 1) * 36 + wid * 3) : (P2_FRAG + wid * 3);
      else             fid = (t < 6) ? ((t + 1) * 36 + (4 + wid) * 3) : (P2_FRAG + (4 + wid) * 3);
      #pragma unroll
      for (int gg = 0; gg < 3; ++gg)
        gload(wsl + (size_t)(fid + gg) * 512, ring + islot * 1536 + gg * 512);
      // consume 4 steps (slots 4g..4g+3)
      #pragma unroll
      for (int so = 0; so < 4; ++so) {
        const int ks = 4 * g + so;
        const uint16_t* sp = ring + ks * 1536 + lane * 8;
        bf16x8 b0 = *(const bf16x8*)(sp);
        bf16x8 b1 = *(const bf16x8*)(sp + 512);
        bf16x8 b2 = *(const bf16x8*)(sp + 1024);
        __builtin_amdgcn_s_setprio(1);
        #pragma unroll
        for (int h = 0; h < 2; ++h) {
          bf16x8 av = (ks < 8) ? xa[h][ks] : ha[h][ks - 8];
          aR[h] = MFMA(av, b0, aR[h]);
          aZ[h] = MFMA(av, b1, aZ[h]);
          if (ks < 8) aNi[h] = MFMA(av, b2, aNi[h]);
          else        aNh[h] = MFMA(av, b2, aNh[h]);
        }
        __builtin_amdgcn_s_setprio(0);
      }
      WAIT_VM3;                                // own prev-group loads landed
      BAR;                                     // union: next 4 slots ready
    }
    // elementwise GRU cell -> HsNew written in place into lT (bf16)
    int c = t * 16 + cl;
    #pragma unroll
    for (int h = 0; h < 2; ++h) {
      #pragma unroll
      for (int r = 0; r < 4; ++r) {
        int row = h * 16 + q * 4 + r;
        int bo = row * 256 + ((c * 2) ^ ((row & 7) << 4));
        float hsp = bf2f(*(const uint16_t*)((const char*)lT + bo));
        float rr = sigmoidf_(aR[h][r]);
        float zz = sigmoidf_(aZ[h][r]);
        float nn = tanhf_(aNi[h][r] + rr * aNh[h][r]);
        float hsn = (1.f - zz) * nn + zz * hsp;
        *(uint16_t*)((char*)lT + bo) = f2bf(hsn);
      }
    }
  }

  // ---- boundary: HsNew frags out of lT, then stage Hp into lT (wave-private) ----
  bf16x8 na[2][4];
  #pragma unroll
  for (int h = 0; h < 2; ++h) {
    int row = h * 16 + cl;
    #pragma unroll
    for (int ks = 0; ks < 4; ++ks) {
      int bo = row * 256 + (((ks * 64) + q * 16) ^ ((row & 7) << 4));
      na[h][ks] = *(const bf16x8*)((const char*)lT + bo);
    }
  }
  WAIT_LGKM0;                                  // na in regs before overwrite
  #pragma unroll
  for (int h = 0; h < 2; ++h) {
    int row = h * 16 + cl;
    #pragma unroll
    for (int ks = 0; ks < 4; ++ks) {
      int bo = row * 256 + (((ks * 64) + q * 16) ^ ((row & 7) << 4));
      *(bf16x8*)((char*)lT + bo) = pa[h][ks];
    }
  }

  // =========================== PASS 2 (task head) ===========================
  // 16 steps per t -> slot base drifts by 4 (mod 12) per t; address-only runtime.
  int sb = 0;
  #pragma unroll 1
  for (int t = 0; t < 7; ++t) {
    f32x4 aZ[2], aR[2], aNa[2], aNb[2];
    #pragma unroll
    for (int h = 0; h < 2; ++h) { aZ[h] = (f32x4)(0.f); aR[h] = (f32x4)(0.f); aNa[h] = (f32x4)(0.f); aNb[h] = (f32x4)(0.f); }
    #pragma unroll
    for (int g = 0; g < 4; ++g) {
      // issue step (t*16 + 4g + 8 + wid) of pass2
      int fid;
      if (g == 0)      fid = P2_FRAG + t * 48 + (8 + wid) * 3;
      else if (g == 1) fid = P2_FRAG + t * 48 + (12 + wid) * 3;
      else if (g == 2) fid = (t < 6) ? (P2_FRAG + (t + 1) * 48 + wid * 3) : P2_FRAG;       // tail clamp
      else             fid = (t < 6) ? (P2_FRAG + (t + 1) * 48 + (4 + wid) * 3) : P2_FRAG; // tail clamp
      int islot = sb + 4 * g + 8 + wid;
      if (islot >= NSLOT) islot -= NSLOT;
      if (islot >= NSLOT) islot -= NSLOT;
      #pragma unroll
      for (int gg = 0; gg < 3; ++gg)
        gload(wsl + (size_t)(fid + gg) * 512, ring + islot * 1536 + gg * 512);
      // consume 4 steps (slots sb+4g .. +3 mod 12)
      int cb = sb + 4 * g;
      if (cb >= NSLOT) cb -= NSLOT;
      #pragma unroll
      for (int so = 0; so < 4; ++so) {
        const int ks = 4 * g + so;
        int sl = cb + so;
        if (sl >= NSLOT) sl -= NSLOT;
        const uint16_t* sp = ring + sl * 1536 + lane * 8;
        bf16x8 b0 = *(const bf16x8*)(sp);
        bf16x8 b1 = *(const bf16x8*)(sp + 512);
        bf16x8 b2 = *(const bf16x8*)(sp + 1024);
        __builtin_amdgcn_s_setprio(1);
        #pragma unroll
        for (int h = 0; h < 2; ++h) {
          bf16x8 av = (ks < 8) ? xa[h][ks] : (ks < 12) ? pa[h][ks - 8] : na[h][ks - 12];
          aZ[h] = MFMA(av, b0, aZ[h]);
          aR[h] = MFMA(av, b1, aR[h]);
          if (ks < 8)       aNa[h] = MFMA(av, b2, aNa[h]);
          else if (ks < 12) aNb[h] = MFMA(av, b2, aNb[h]);
          else              aNa[h] = MFMA(av, b2, aNa[h]);
        }
        __builtin_amdgcn_s_setprio(0);
      }
      WAIT_VM3;
      BAR;
    }
    // elementwise + store (hpv from lT)
    int c = t * 16 + cl;
    bool valid = c < H_DIM;
    #pragma unroll
    for (int h = 0; h < 2; ++h) {
      #pragma unroll
      for (int r = 0; r < 4; ++r) {
        int row = h * 16 + q * 4 + r;
        int bo = row * 256 + ((c * 2) ^ ((row & 7) << 4));
        float hpv = bf2f(*(const uint16_t*)((const char*)lT + bo));
        float z2 = sigmoidf_(aZ[h][r]);
        float r2 = sigmoidf_(aR[h][r]);
        float nm = tanhf_(aNa[h][r] + r2 * aNb[h][r]);
        float hnew = (1.f - z2) * nm + z2 * hpv;
        if (valid) out[(size_t)(rowbase + row) * H_DIM + c] = hnew;
      }
    }
    sb += 4;
    if (sb >= NSLOT) sb -= NSLOT;
  }
}

extern "C" void kernel_launch(void* const* d_in, const int* in_sizes, int n_in,
                              void* d_out, int out_size, void* d_ws, size_t ws_size,
                              hipStream_t stream) {
  const float* x    = (const float*)d_in[0];
  const float* h_p  = (const float*)d_in[1];
  const float* h_s  = (const float*)d_in[2];
  const float* Wi   = (const float*)d_in[3];
  const float* Wh   = (const float*)d_in[4];
  const float* bi   = (const float*)d_in[5];
  const float* bh   = (const float*)d_in[6];
  const float* W_z  = (const float*)d_in[7];
  const float* U_z  = (const float*)d_in[8];
  const float* Us_z = (const float*)d_in[9];
  const float* W_r  = (const float*)d_in[10];
  const float* U_r  = (const float*)d_in[11];
  const float* Us_r = (const float*)d_in[12];
  const float* W_hn = (const float*)d_in[13];
  const float* U_hn = (const float*)d_in[14];
  const float* Us_hn= (const float*)d_in[15];
  uint16_t* ws = (uint16_t*)d_ws;
  float* out = (float*)d_out;

  int rows = in_sizes[0] / D_IN;          // 262144
  prepack_kernel<<<(TOTAL_E + 255) / 256, 256, 0, stream>>>(
      Wi, Wh, W_z, U_z, Us_z, W_r, U_r, Us_r, W_hn, U_hn, Us_hn, bi, bh, ws);
  gru_fused<<<rows / BM, NTHREADS, 0, stream>>>(x, h_p, h_s, ws, out);
}

// Round 11
// 271.095 us; speedup vs baseline: 1.8353x; 1.1291x over previous
//
#include <hip/hip_runtime.h>
#include <stdint.h>

#define D_IN 250
#define H_DIM 100
#define RPW 32            // rows per wave
#define NTHREADS 256      // 4 waves
#define BM (4*RPW)        // 128 rows per block

// ws layout: 588 fragments of 512 bf16 elems each.
// pass1 frag id = t*36 + ks*3 + g      (t 0..6, ks 0..11 [0-7 X, 8-11 Hs], g 0..2 [r,z,n])
// pass2 frag id = 252 + t*48 + ks*3+g  (ks 0..15 [0-7 X, 8-11 Hp, 12-15 HsN], g [z,r,hn])
#define P2_FRAG 252
#define TOTAL_E ((252 + 336) * 512)     // 301056 elems

#define NSLOT 8           // LDS ring slots (3 KB each); slot = global_step & 7

typedef __bf16 bf16x8 __attribute__((ext_vector_type(8)));
typedef float f32x4 __attribute__((ext_vector_type(4)));

static __device__ __forceinline__ uint16_t f2bf(float f) {
  uint32_t u = __builtin_bit_cast(uint32_t, f);
  u = (u + 0x7FFFu + ((u >> 16) & 1u)) >> 16;
  return (uint16_t)u;
}
static __device__ __forceinline__ float bf2f(uint16_t h) {
  uint32_t u = ((uint32_t)h) << 16;
  return __builtin_bit_cast(float, u);
}
static __device__ __forceinline__ float sigmoidf_(float x) {
  return 1.0f / (1.0f + __expf(-x));
}
static __device__ __forceinline__ float tanhf_(float x) {
  return 2.0f / (1.0f + __expf(-2.0f * x)) - 1.0f;
}

// ---------------- weight prepack: fp32 -> bf16 B-fragment layout -------------
__global__ void prepack_kernel(const float* __restrict__ Wi, const float* __restrict__ Wh,
                               const float* __restrict__ W_z, const float* __restrict__ U_z,
                               const float* __restrict__ Us_z, const float* __restrict__ W_r,
                               const float* __restrict__ U_r, const float* __restrict__ Us_r,
                               const float* __restrict__ W_hn, const float* __restrict__ U_hn,
                               const float* __restrict__ Us_hn, const float* __restrict__ bi,
                               const float* __restrict__ bh, uint16_t* __restrict__ ws) {
  int idx = blockIdx.x * blockDim.x + threadIdx.x;
  if (idx >= TOTAL_E) return;
  int f = idx >> 9;
  int a = idx & 511;
  int lane = a >> 3, j = a & 7;
  int kloc = ((lane >> 4) << 3) + j;
  int cl = lane & 15;
  float val = 0.f;
  if (f < P2_FRAG) {
    int g = f % 3, ks = (f / 3) % 12, t = f / 36;
    int c = t * 16 + cl;
    if (c < H_DIM) {
      if (ks < 8) {
        int k = ks * 32 + kloc;
        if (k < D_IN)       val = Wi[(size_t)(g * H_DIM + c) * D_IN + k];
        else if (k == D_IN) val = bi[g * H_DIM + c];
      } else {
        int k = (ks - 8) * 32 + kloc;
        if (k < H_DIM)       val = Wh[(size_t)(g * H_DIM + c) * H_DIM + k];
        else if (k == H_DIM) val = bh[g * H_DIM + c];
      }
    }
  } else {
    int f2 = f - P2_FRAG;
    int g = f2 % 3, ks = (f2 / 3) % 16, t = f2 / 48;
    int c = t * 16 + cl;
    if (c < H_DIM) {
      if (ks < 8) {
        int k = ks * 32 + kloc;
        const float* W = g == 0 ? W_z : g == 1 ? W_r : W_hn;
        if (k < D_IN) val = W[(size_t)c * D_IN + k];
      } else if (ks < 12) {
        int k = (ks - 8) * 32 + kloc;
        const float* W = g == 0 ? U_z : g == 1 ? U_r : U_hn;
        if (k < H_DIM) val = W[(size_t)c * H_DIM + k];
      } else {
        int k = (ks - 12) * 32 + kloc;
        const float* W = g == 0 ? Us_z : g == 1 ? Us_r : Us_hn;
        if (k < H_DIM) val = W[(size_t)c * H_DIM + k];
      }
    }
  }
  ws[idx] = f2bf(val);
}

// ------------------------- A-fragment direct loaders -------------------------
static __device__ __forceinline__ bf16x8 xfrag(const float* __restrict__ xr, int ks, int q) {
  int c0 = ks * 32 + q * 8;
  bf16x8 a;
  if (c0 < 248) {
    #pragma unroll
    for (int i = 0; i < 4; ++i) {
      float2 f = *(const float2*)(xr + c0 + 2 * i);
      a[2 * i] = (__bf16)f.x; a[2 * i + 1] = (__bf16)f.y;
    }
  } else {                    // cols 248,249 valid; 250 = bias 1.0; rest 0
    float2 f = *(const float2*)(xr + 248);
    a[0] = (__bf16)f.x; a[1] = (__bf16)f.y; a[2] = (__bf16)1.0f;
    a[3] = (__bf16)0.0f; a[4] = (__bf16)0.0f; a[5] = (__bf16)0.0f;
    a[6] = (__bf16)0.0f; a[7] = (__bf16)0.0f;
  }
  return a;
}
static __device__ __forceinline__ bf16x8 hfrag(const float* __restrict__ hr, int ks, int q, float bias) {
  int c0 = ks * 32 + q * 8;
  bf16x8 a;
  #pragma unroll
  for (int i = 0; i < 8; ++i) a[i] = (__bf16)0.0f;
  if (c0 <= 88) {
    #pragma unroll
    for (int i = 0; i < 4; ++i) {
      float2 f = *(const float2*)(hr + c0 + 2 * i);
      a[2 * i] = (__bf16)f.x; a[2 * i + 1] = (__bf16)f.y;
    }
  } else if (c0 == 96) {      // cols 96..99 valid; 100 = bias; rest 0
    float2 f0 = *(const float2*)(hr + 96);
    float2 f1 = *(const float2*)(hr + 98);
    a[0] = (__bf16)f0.x; a[1] = (__bf16)f0.y; a[2] = (__bf16)f1.x; a[3] = (__bf16)f1.y;
    a[4] = (__bf16)bias;
  }
  return a;
}

#define MFMA(A, B, C) __builtin_amdgcn_mfma_f32_16x16x32_bf16((A), (B), (C), 0, 0, 0)

// --------------- block-shared B ring: global -> LDS DMA ----------------------
typedef const __attribute__((address_space(1))) unsigned int* gp1_t;
typedef __attribute__((address_space(3))) unsigned int* lp3_t;

static __device__ __forceinline__ void gload(const uint16_t* gsrc, uint16_t* ldst) {
  __builtin_amdgcn_global_load_lds((gp1_t)gsrc, (lp3_t)ldst, 16, 0, 0);
}
#define WAIT_VM2   asm volatile("s_waitcnt vmcnt(2)" ::: "memory")
#define WAIT_VM0   asm volatile("s_waitcnt vmcnt(0)" ::: "memory")
#define WAIT_LGKM0 asm volatile("s_waitcnt lgkmcnt(0)" ::: "memory")
#define BAR        do { __builtin_amdgcn_s_barrier(); __builtin_amdgcn_sched_barrier(0); } while (0)

// ---------------------------- fused GRU kernel -------------------------------
// Round-8 structure + register double-buffered B reads (read one group ahead).
// slot == global_step & 7. Waves 0-2 issue; all 4 consume. 2 K-steps/barrier.
__global__ __launch_bounds__(NTHREADS, 2) void gru_fused(
    const float* __restrict__ x, const float* __restrict__ hp_g,
    const float* __restrict__ hs_g, const uint16_t* __restrict__ ws,
    float* __restrict__ out) {
  __shared__ __align__(16) uint16_t ldsT[4 * RPW * 128];   // 32 KB: Hs->HsNew, then Hp
  __shared__ __align__(16) uint16_t ring[NSLOT * 1536];    // 24 KB: 8 slots x 3 frags

  const int tid = threadIdx.x;
  const int lane = tid & 63, wid = tid >> 6;
  const int q = lane >> 4, cl = lane & 15;
  const int rowbase = blockIdx.x * BM + wid * RPW;
  uint16_t* lT = ldsT + wid * (RPW * 128);
  const uint16_t* wsl = ws + lane * 8;

  // ---- prologue: load ALL A fragments (xa, ha, pa) ----
  bf16x8 xa[2][8], ha[2][4], pa[2][4];
  #pragma unroll
  for (int h = 0; h < 2; ++h) {
    const float* xr = x + (size_t)(rowbase + h * 16 + cl) * D_IN;
    #pragma unroll
    for (int ks = 0; ks < 8; ++ks) xa[h][ks] = xfrag(xr, ks, q);
    const float* hr = hs_g + (size_t)(rowbase + h * 16 + cl) * H_DIM;
    #pragma unroll
    for (int ks = 0; ks < 4; ++ks) ha[h][ks] = hfrag(hr, ks, q, 1.0f);
    const float* pr = hp_g + (size_t)(rowbase + h * 16 + cl) * H_DIM;
    #pragma unroll
    for (int ks = 0; ks < 4; ++ks) pa[h][ks] = hfrag(pr, ks, q, 0.0f);
  }

  // stage Hs (bf16) into lT in the A-layout (swizzled); covers cols 0..127
  #pragma unroll
  for (int h = 0; h < 2; ++h) {
    int row = h * 16 + cl;
    #pragma unroll
    for (int ks = 0; ks < 4; ++ks) {
      int bo = row * 256 + (((ks * 64) + q * 16) ^ ((row & 7) << 4));
      *(bf16x8*)((char*)lT + bo) = ha[h][ks];
    }
  }

  // ring prologue: issue steps 0..5 into slots 0..5 (wave w loads gate w)
  if (wid < 3) {
    #pragma unroll
    for (int s = 0; s < 6; ++s)
      gload(wsl + (size_t)(s * 3 + wid) * 512, ring + s * 1536 + wid * 512);
    WAIT_VM2;                                  // steps 0..3 landed
  }
  BAR;

  // read-ahead: steps 0,1 into cur regs
  bf16x8 c00, c01, c02, c10, c11, c12;
  {
    const uint16_t* sp0 = ring + 0 * 1536 + lane * 8;
    const uint16_t* sp1 = ring + 1 * 1536 + lane * 8;
    c00 = *(const bf16x8*)(sp0); c01 = *(const bf16x8*)(sp0 + 512); c02 = *(const bf16x8*)(sp0 + 1024);
    c10 = *(const bf16x8*)(sp1); c11 = *(const bf16x8*)(sp1 + 512); c12 = *(const bf16x8*)(sp1 + 1024);
  }

  // =========================== PASS 1 (GRU cell) ============================
  #pragma unroll 1
  for (int t = 0; t < 7; ++t) {
    const int tb = (t & 1) << 2;               // slot base = (t*12) & 7
    f32x4 aR[2], aZ[2], aNi[2], aNh[2];
    #pragma unroll
    for (int h = 0; h < 2; ++h) { aR[h] = (f32x4)(0.f); aZ[h] = (f32x4)(0.f); aNi[h] = (f32x4)(0.f); aNh[h] = (f32x4)(0.f); }
    #pragma unroll
    for (int ks = 0; ks < 12; ks += 2) {
      // issue DMA for steps s+6, s+7 (gate wid of each)
      if (wid < 3) {
        const int k6 = ks + 6, k7 = ks + 7;
        int f6 = (k6 < 12) ? (t * 36 + k6 * 3)
               : (t < 6 ? ((t + 1) * 36 + (k6 - 12) * 3) : (P2_FRAG + (k6 - 12) * 3));
        int f7 = (k7 < 12) ? (t * 36 + k7 * 3)
               : (t < 6 ? ((t + 1) * 36 + (k7 - 12) * 3) : (P2_FRAG + (k7 - 12) * 3));
        gload(wsl + (size_t)(f6 + wid) * 512, ring + ((tb + ks + 6) & 7) * 1536 + wid * 512);
        gload(wsl + (size_t)(f7 + wid) * 512, ring + ((tb + ks + 7) & 7) * 1536 + wid * 512);
      }
      // MFMA on pre-loaded cur regs (steps ks, ks+1)
      __builtin_amdgcn_s_setprio(1);
      #pragma unroll
      for (int h = 0; h < 2; ++h) {
        bf16x8 av0 = (ks < 8) ? xa[h][ks] : ha[h][ks - 8];
        aR[h] = MFMA(av0, c00, aR[h]);
        aZ[h] = MFMA(av0, c01, aZ[h]);
        if (ks < 8) aNi[h] = MFMA(av0, c02, aNi[h]);
        else        aNh[h] = MFMA(av0, c02, aNh[h]);
        bf16x8 av1 = (ks + 1 < 8) ? xa[h][ks + 1] : ha[h][ks + 1 - 8];
        aR[h] = MFMA(av1, c10, aR[h]);
        aZ[h] = MFMA(av1, c11, aZ[h]);
        if (ks + 1 < 8) aNi[h] = MFMA(av1, c12, aNi[h]);
        else            aNh[h] = MFMA(av1, c12, aNh[h]);
      }
      __builtin_amdgcn_s_setprio(0);
      // read-ahead steps ks+2, ks+3 (landing guaranteed by previous group's wait)
      {
        const uint16_t* sp0 = ring + ((tb + ks + 2) & 7) * 1536 + lane * 8;
        const uint16_t* sp1 = ring + ((tb + ks + 3) & 7) * 1536 + lane * 8;
        c00 = *(const bf16x8*)(sp0); c01 = *(const bf16x8*)(sp0 + 512); c02 = *(const bf16x8*)(sp0 + 1024);
        c10 = *(const bf16x8*)(sp1); c11 = *(const bf16x8*)(sp1 + 512); c12 = *(const bf16x8*)(sp1 + 1024);
      }
      if (wid < 3) WAIT_VM2;                   // next group's read-ahead slots landed
      BAR;
    }
    // elementwise GRU cell -> HsNew written in place into lT (bf16)
    int c = t * 16 + cl;
    #pragma unroll
    for (int h = 0; h < 2; ++h) {
      #pragma unroll
      for (int r = 0; r < 4; ++r) {
        int row = h * 16 + q * 4 + r;
        int bo = row * 256 + ((c * 2) ^ ((row & 7) << 4));
        float hsp = bf2f(*(const uint16_t*)((const char*)lT + bo));
        float rr = sigmoidf_(aR[h][r]);
        float zz = sigmoidf_(aZ[h][r]);
        float nn = tanhf_(aNi[h][r] + rr * aNh[h][r]);
        float hsn = (1.f - zz) * nn + zz * hsp;
        *(uint16_t*)((char*)lT + bo) = f2bf(hsn);
      }
    }
  }

  // ---- boundary: HsNew frags out of lT, then stage Hp into lT (wave-private) ----
  bf16x8 na[2][4];
  #pragma unroll
  for (int h = 0; h < 2; ++h) {
    int row = h * 16 + cl;
    #pragma unroll
    for (int ks = 0; ks < 4; ++ks) {
      int bo = row * 256 + (((ks * 64) + q * 16) ^ ((row & 7) << 4));
      na[h][ks] = *(const bf16x8*)((const char*)lT + bo);
    }
  }
  WAIT_LGKM0;                                  // na in regs before overwrite
  #pragma unroll
  for (int h = 0; h < 2; ++h) {
    int row = h * 16 + cl;
    #pragma unroll
    for (int ks = 0; ks < 4; ++ks) {
      int bo = row * 256 + (((ks * 64) + q * 16) ^ ((row & 7) << 4));
      *(bf16x8*)((char*)lT + bo) = pa[h][ks];
    }
  }

  // =========================== PASS 2 (task head) ===========================
  // global step = 84 + t*16 + ks; slot = (4 + ks) & 7 (static: 16 = 0 mod 8)
  #pragma unroll 1
  for (int t = 0; t < 7; ++t) {
    f32x4 aZ[2], aR[2], aNa[2], aNb[2];
    #pragma unroll
    for (int h = 0; h < 2; ++h) { aZ[h] = (f32x4)(0.f); aR[h] = (f32x4)(0.f); aNa[h] = (f32x4)(0.f); aNb[h] = (f32x4)(0.f); }
    #pragma unroll
    for (int ks = 0; ks < 16; ks += 2) {
      if (wid < 3) {
        const int k6 = ks + 6, k7 = ks + 7;
        int f6 = (k6 < 16) ? (P2_FRAG + t * 48 + k6 * 3)
               : (t < 6 ? (P2_FRAG + (t + 1) * 48 + (k6 - 16) * 3) : P2_FRAG);   // tail clamp
        int f7 = (k7 < 16) ? (P2_FRAG + t * 48 + k7 * 3)
               : (t < 6 ? (P2_FRAG + (t + 1) * 48 + (k7 - 16) * 3) : P2_FRAG);   // tail clamp
        gload(wsl + (size_t)(f6 + wid) * 512, ring + ((4 + ks + 6) & 7) * 1536 + wid * 512);
        gload(wsl + (size_t)(f7 + wid) * 512, ring + ((4 + ks + 7) & 7) * 1536 + wid * 512);
      }
      __builtin_amdgcn_s_setprio(1);
      #pragma unroll
      for (int h = 0; h < 2; ++h) {
        bf16x8 av0 = (ks < 8) ? xa[h][ks] : (ks < 12) ? pa[h][ks - 8] : na[h][ks - 12];
        aZ[h] = MFMA(av0, c00, aZ[h]);
        aR[h] = MFMA(av0, c01, aR[h]);
        if (ks < 8)       aNa[h] = MFMA(av0, c02, aNa[h]);
        else if (ks < 12) aNb[h] = MFMA(av0, c02, aNb[h]);
        else              aNa[h] = MFMA(av0, c02, aNa[h]);
        bf16x8 av1 = (ks + 1 < 8) ? xa[h][ks + 1] : (ks + 1 < 12) ? pa[h][ks + 1 - 8] : na[h][ks + 1 - 12];
        aZ[h] = MFMA(av1, c10, aZ[h]);
        aR[h] = MFMA(av1, c11, aR[h]);
        if (ks + 1 < 8)       aNa[h] = MFMA(av1, c12, aNa[h]);
        else if (ks + 1 < 12) aNb[h] = MFMA(av1, c12, aNb[h]);
        else                  aNa[h] = MFMA(av1, c12, aNa[h]);
      }
      __builtin_amdgcn_s_setprio(0);
      // read-ahead steps ks+2, ks+3
      {
        const uint16_t* sp0 = ring + ((4 + ks + 2) & 7) * 1536 + lane * 8;
        const uint16_t* sp1 = ring + ((4 + ks + 3) & 7) * 1536 + lane * 8;
        c00 = *(const bf16x8*)(sp0); c01 = *(const bf16x8*)(sp0 + 512); c02 = *(const bf16x8*)(sp0 + 1024);
        c10 = *(const bf16x8*)(sp1); c11 = *(const bf16x8*)(sp1 + 512); c12 = *(const bf16x8*)(sp1 + 1024);
      }
      if (wid < 3) WAIT_VM2;
      BAR;
    }
    // elementwise + store (hpv from lT)
    int c = t * 16 + cl;
    bool valid = c < H_DIM;
    #pragma unroll
    for (int h = 0; h < 2; ++h) {
      #pragma unroll
      for (int r = 0; r < 4; ++r) {
        int row = h * 16 + q * 4 + r;
        int bo = row * 256 + ((c * 2) ^ ((row & 7) << 4));
        float hpv = bf2f(*(const uint16_t*)((const char*)lT + bo));
        float z2 = sigmoidf_(aZ[h][r]);
        float r2 = sigmoidf_(aR[h][r]);
        float nm = tanhf_(aNa[h][r] + r2 * aNb[h][r]);
        float hnew = (1.f - z2) * nm + z2 * hpv;
        if (valid) out[(size_t)(rowbase + row) * H_DIM + c] = hnew;
      }
    }
  }

  // drain outstanding DMAs (protect reallocated LDS from late landings)
  WAIT_VM0;
}

extern "C" void kernel_launch(void* const* d_in, const int* in_sizes, int n_in,
                              void* d_out, int out_size, void* d_ws, size_t ws_size,
                              hipStream_t stream) {
  const float* x    = (const float*)d_in[0];
  const float* h_p  = (const float*)d_in[1];
  const float* h_s  = (const float*)d_in[2];
  const float* Wi   = (const float*)d_in[3];
  const float* Wh   = (const float*)d_in[4];
  const float* bi   = (const float*)d_in[5];
  const float* bh   = (const float*)d_in[6];
  const float* W_z  = (const float*)d_in[7];
  const float* U_z  = (const float*)d_in[8];
  const float* Us_z = (const float*)d_in[9];
  const float* W_r  = (const float*)d_in[10];
  const float* U_r  = (const float*)d_in[11];
  const float* Us_r = (const float*)d_in[12];
  const float* W_hn = (const float*)d_in[13];
  const float* U_hn = (const float*)d_in[14];
  const float* Us_hn= (const float*)d_in[15];
  uint16_t* ws = (uint16_t*)d_ws;
  float* out = (float*)d_out;

  int rows = in_sizes[0] / D_IN;          // 262144
  prepack_kernel<<<(TOTAL_E + 255) / 256, 256, 0, stream>>>(
      Wi, Wh, W_z, U_z, Us_z, W_r, U_r, Us_r, W_hn, U_hn, Us_hn, bi, bh, ws);
  gru_fused<<<rows / BM, NTHREADS, 0, stream>>>(x, h_p, h_s, ws, out);
}

// Round 12
// 270.356 us; speedup vs baseline: 1.8403x; 1.0027x over previous
//
#include <hip/hip_runtime.h>
#include <stdint.h>

#define D_IN 250
#define H_DIM 100
#define RPW 32            // rows per wave
#define NTHREADS 256      // 4 waves
#define BM (4*RPW)        // 128 rows per block

// ws layout: 588 fragments of 512 bf16 elems each.
// pass1 frag id = t*36 + ks*3 + g      (t 0..6, ks 0..11 [0-7 X, 8-11 Hs], g 0..2 [r,z,n])
// pass2 frag id = 252 + t*48 + ks*3+g  (ks 0..15 [0-7 X, 8-11 Hp, 12-15 HsN], g [z,r,hn])
#define P2_FRAG 252
#define TOTAL_E ((252 + 336) * 512)     // 301056 elems

#define NSLOT 6           // LDS ring slots (3 KB each); slot = global_step mod 6

typedef __bf16 bf16x8 __attribute__((ext_vector_type(8)));
typedef float f32x4 __attribute__((ext_vector_type(4)));

static __device__ __forceinline__ uint16_t f2bf(float f) {
  uint32_t u = __builtin_bit_cast(uint32_t, f);
  u = (u + 0x7FFFu + ((u >> 16) & 1u)) >> 16;
  return (uint16_t)u;
}
static __device__ __forceinline__ float bf2f(uint16_t h) {
  uint32_t u = ((uint32_t)h) << 16;
  return __builtin_bit_cast(float, u);
}
static __device__ __forceinline__ float sigmoidf_(float x) {
  return 1.0f / (1.0f + __expf(-x));
}
static __device__ __forceinline__ float tanhf_(float x) {
  return 2.0f / (1.0f + __expf(-2.0f * x)) - 1.0f;
}

// ---------------- weight prepack: fp32 -> bf16 B-fragment layout -------------
__global__ void prepack_kernel(const float* __restrict__ Wi, const float* __restrict__ Wh,
                               const float* __restrict__ W_z, const float* __restrict__ U_z,
                               const float* __restrict__ Us_z, const float* __restrict__ W_r,
                               const float* __restrict__ U_r, const float* __restrict__ Us_r,
                               const float* __restrict__ W_hn, const float* __restrict__ U_hn,
                               const float* __restrict__ Us_hn, const float* __restrict__ bi,
                               const float* __restrict__ bh, uint16_t* __restrict__ ws) {
  int idx = blockIdx.x * blockDim.x + threadIdx.x;
  if (idx >= TOTAL_E) return;
  int f = idx >> 9;
  int a = idx & 511;
  int lane = a >> 3, j = a & 7;
  int kloc = ((lane >> 4) << 3) + j;
  int cl = lane & 15;
  float val = 0.f;
  if (f < P2_FRAG) {
    int g = f % 3, ks = (f / 3) % 12, t = f / 36;
    int c = t * 16 + cl;
    if (c < H_DIM) {
      if (ks < 8) {
        int k = ks * 32 + kloc;
        if (k < D_IN)       val = Wi[(size_t)(g * H_DIM + c) * D_IN + k];
        else if (k == D_IN) val = bi[g * H_DIM + c];
      } else {
        int k = (ks - 8) * 32 + kloc;
        if (k < H_DIM)       val = Wh[(size_t)(g * H_DIM + c) * H_DIM + k];
        else if (k == H_DIM) val = bh[g * H_DIM + c];
      }
    }
  } else {
    int f2 = f - P2_FRAG;
    int g = f2 % 3, ks = (f2 / 3) % 16, t = f2 / 48;
    int c = t * 16 + cl;
    if (c < H_DIM) {
      if (ks < 8) {
        int k = ks * 32 + kloc;
        const float* W = g == 0 ? W_z : g == 1 ? W_r : W_hn;
        if (k < D_IN) val = W[(size_t)c * D_IN + k];
      } else if (ks < 12) {
        int k = (ks - 8) * 32 + kloc;
        const float* W = g == 0 ? U_z : g == 1 ? U_r : U_hn;
        if (k < H_DIM) val = W[(size_t)c * H_DIM + k];
      } else {
        int k = (ks - 12) * 32 + kloc;
        const float* W = g == 0 ? Us_z : g == 1 ? Us_r : Us_hn;
        if (k < H_DIM) val = W[(size_t)c * H_DIM + k];
      }
    }
  }
  ws[idx] = f2bf(val);
}

// ------------------------- A-fragment direct loaders -------------------------
static __device__ __forceinline__ bf16x8 xfrag(const float* __restrict__ xr, int ks, int q) {
  int c0 = ks * 32 + q * 8;
  bf16x8 a;
  if (c0 < 248) {
    #pragma unroll
    for (int i = 0; i < 4; ++i) {
      float2 f = *(const float2*)(xr + c0 + 2 * i);
      a[2 * i] = (__bf16)f.x; a[2 * i + 1] = (__bf16)f.y;
    }
  } else {                    // cols 248,249 valid; 250 = bias 1.0; rest 0
    float2 f = *(const float2*)(xr + 248);
    a[0] = (__bf16)f.x; a[1] = (__bf16)f.y; a[2] = (__bf16)1.0f;
    a[3] = (__bf16)0.0f; a[4] = (__bf16)0.0f; a[5] = (__bf16)0.0f;
    a[6] = (__bf16)0.0f; a[7] = (__bf16)0.0f;
  }
  return a;
}
static __device__ __forceinline__ bf16x8 hfrag(const float* __restrict__ hr, int ks, int q, float bias) {
  int c0 = ks * 32 + q * 8;
  bf16x8 a;
  #pragma unroll
  for (int i = 0; i < 8; ++i) a[i] = (__bf16)0.0f;
  if (c0 <= 88) {
    #pragma unroll
    for (int i = 0; i < 4; ++i) {
      float2 f = *(const float2*)(hr + c0 + 2 * i);
      a[2 * i] = (__bf16)f.x; a[2 * i + 1] = (__bf16)f.y;
    }
  } else if (c0 == 96) {      // cols 96..99 valid; 100 = bias; rest 0
    float2 f0 = *(const float2*)(hr + 96);
    float2 f1 = *(const float2*)(hr + 98);
    a[0] = (__bf16)f0.x; a[1] = (__bf16)f0.y; a[2] = (__bf16)f1.x; a[3] = (__bf16)f1.y;
    a[4] = (__bf16)bias;
  }
  return a;
}

#define MFMA(A, B, C) __builtin_amdgcn_mfma_f32_16x16x32_bf16((A), (B), (C), 0, 0, 0)

// --------------- block-shared B ring: global -> LDS DMA ----------------------
typedef const __attribute__((address_space(1))) unsigned int* gp1_t;
typedef __attribute__((address_space(3))) unsigned int* lp3_t;

static __device__ __forceinline__ void gload(const uint16_t* gsrc, uint16_t* ldst) {
  __builtin_amdgcn_global_load_lds((gp1_t)gsrc, (lp3_t)ldst, 16, 0, 0);
}
#define WAIT_VM2   asm volatile("s_waitcnt vmcnt(2)" ::: "memory")
#define WAIT_VM0   asm volatile("s_waitcnt vmcnt(0)" ::: "memory")
#define WAIT_LGKM0 asm volatile("s_waitcnt lgkmcnt(0)" ::: "memory")
#define BAR        do { __builtin_amdgcn_s_barrier(); __builtin_amdgcn_sched_barrier(0); } while (0)

// ---------------------------- fused GRU kernel -------------------------------
// Round-8 schedule with a 6-slot ring (50 KB LDS total -> 3 blocks/CU).
// Waves 0-2 issue DMA at depth 4 (vmcnt(2)); all 4 consume; 2 K-steps/barrier.
__global__ __launch_bounds__(NTHREADS, 2) void gru_fused(
    const float* __restrict__ x, const float* __restrict__ hp_g,
    const float* __restrict__ hs_g, const uint16_t* __restrict__ ws,
    float* __restrict__ out) {
  __shared__ __align__(16) uint16_t ldsT[4 * RPW * 128];   // 32 KB: Hs->HsNew, then Hp
  __shared__ __align__(16) uint16_t ring[NSLOT * 1536];    // 18 KB: 6 slots x 3 frags

  const int tid = threadIdx.x;
  const int lane = tid & 63, wid = tid >> 6;
  const int q = lane >> 4, cl = lane & 15;
  const int rowbase = blockIdx.x * BM + wid * RPW;
  uint16_t* lT = ldsT + wid * (RPW * 128);
  const uint16_t* wsl = ws + lane * 8;

  // ---- prologue: load ALL A fragments (xa, ha, pa) ----
  bf16x8 xa[2][8], ha[2][4], pa[2][4];
  #pragma unroll
  for (int h = 0; h < 2; ++h) {
    const float* xr = x + (size_t)(rowbase + h * 16 + cl) * D_IN;
    #pragma unroll
    for (int ks = 0; ks < 8; ++ks) xa[h][ks] = xfrag(xr, ks, q);
    const float* hr = hs_g + (size_t)(rowbase + h * 16 + cl) * H_DIM;
    #pragma unroll
    for (int ks = 0; ks < 4; ++ks) ha[h][ks] = hfrag(hr, ks, q, 1.0f);
    const float* pr = hp_g + (size_t)(rowbase + h * 16 + cl) * H_DIM;
    #pragma unroll
    for (int ks = 0; ks < 4; ++ks) pa[h][ks] = hfrag(pr, ks, q, 0.0f);
  }

  // stage Hs (bf16) into lT in the A-layout (swizzled); covers cols 0..127
  #pragma unroll
  for (int h = 0; h < 2; ++h) {
    int row = h * 16 + cl;
    #pragma unroll
    for (int ks = 0; ks < 4; ++ks) {
      int bo = row * 256 + (((ks * 64) + q * 16) ^ ((row & 7) << 4));
      *(bf16x8*)((char*)lT + bo) = ha[h][ks];
    }
  }

  // ring prologue: issue steps 0..3 into slots 0..3 (wave w loads gate w)
  if (wid < 3) {
    #pragma unroll
    for (int s = 0; s < 4; ++s)
      gload(wsl + (size_t)(s * 3 + wid) * 512, ring + s * 1536 + wid * 512);
    WAIT_VM2;                                  // steps 0,1 landed
  }
  BAR;

  // =========================== PASS 1 (GRU cell) ============================
  // 12 steps per t; 12 % 6 == 0 -> slots are compile-time static (= ks % 6).
  #pragma unroll 1
  for (int t = 0; t < 7; ++t) {
    f32x4 aR[2], aZ[2], aNi[2], aNh[2];
    #pragma unroll
    for (int h = 0; h < 2; ++h) { aR[h] = (f32x4)(0.f); aZ[h] = (f32x4)(0.f); aNi[h] = (f32x4)(0.f); aNh[h] = (f32x4)(0.f); }
    #pragma unroll
    for (int ks = 0; ks < 12; ks += 2) {
      // ds_read current steps ks, ks+1 (landing guaranteed 2 groups ago)
      const uint16_t* sp0 = ring + (ks % NSLOT) * 1536 + lane * 8;
      const uint16_t* sp1 = ring + ((ks + 1) % NSLOT) * 1536 + lane * 8;
      bf16x8 a0 = *(const bf16x8*)(sp0);
      bf16x8 a1 = *(const bf16x8*)(sp0 + 512);
      bf16x8 a2 = *(const bf16x8*)(sp0 + 1024);
      bf16x8 b0 = *(const bf16x8*)(sp1);
      bf16x8 b1 = *(const bf16x8*)(sp1 + 512);
      bf16x8 b2 = *(const bf16x8*)(sp1 + 1024);
      // issue DMA for steps ks+4, ks+5 (gate wid of each)
      if (wid < 3) {
        const int k4 = ks + 4, k5 = ks + 5;
        int f4 = (k4 < 12) ? (t * 36 + k4 * 3)
               : (t < 6 ? ((t + 1) * 36 + (k4 - 12) * 3) : (P2_FRAG + (k4 - 12) * 3));
        int f5 = (k5 < 12) ? (t * 36 + k5 * 3)
               : (t < 6 ? ((t + 1) * 36 + (k5 - 12) * 3) : (P2_FRAG + (k5 - 12) * 3));
        gload(wsl + (size_t)(f4 + wid) * 512, ring + (k4 % NSLOT) * 1536 + wid * 512);
        gload(wsl + (size_t)(f5 + wid) * 512, ring + (k5 % NSLOT) * 1536 + wid * 512);
      }
      __builtin_amdgcn_s_setprio(1);
      #pragma unroll
      for (int h = 0; h < 2; ++h) {
        bf16x8 av0 = (ks < 8) ? xa[h][ks] : ha[h][ks - 8];
        aR[h] = MFMA(av0, a0, aR[h]);
        aZ[h] = MFMA(av0, a1, aZ[h]);
        if (ks < 8) aNi[h] = MFMA(av0, a2, aNi[h]);
        else        aNh[h] = MFMA(av0, a2, aNh[h]);
        bf16x8 av1 = (ks + 1 < 8) ? xa[h][ks + 1] : ha[h][ks + 1 - 8];
        aR[h] = MFMA(av1, b0, aR[h]);
        aZ[h] = MFMA(av1, b1, aZ[h]);
        if (ks + 1 < 8) aNi[h] = MFMA(av1, b2, aNi[h]);
        else            aNh[h] = MFMA(av1, b2, aNh[h]);
      }
      __builtin_amdgcn_s_setprio(0);
      if (wid < 3) WAIT_VM2;                   // steps ks+2, ks+3 landed
      BAR;
    }
    // elementwise GRU cell -> HsNew written in place into lT (bf16)
    int c = t * 16 + cl;
    #pragma unroll
    for (int h = 0; h < 2; ++h) {
      #pragma unroll
      for (int r = 0; r < 4; ++r) {
        int row = h * 16 + q * 4 + r;
        int bo = row * 256 + ((c * 2) ^ ((row & 7) << 4));
        float hsp = bf2f(*(const uint16_t*)((const char*)lT + bo));
        float rr = sigmoidf_(aR[h][r]);
        float zz = sigmoidf_(aZ[h][r]);
        float nn = tanhf_(aNi[h][r] + rr * aNh[h][r]);
        float hsn = (1.f - zz) * nn + zz * hsp;
        *(uint16_t*)((char*)lT + bo) = f2bf(hsn);
      }
    }
  }

  // ---- boundary: HsNew frags out of lT, then stage Hp into lT (wave-private) ----
  bf16x8 na[2][4];
  #pragma unroll
  for (int h = 0; h < 2; ++h) {
    int row = h * 16 + cl;
    #pragma unroll
    for (int ks = 0; ks < 4; ++ks) {
      int bo = row * 256 + (((ks * 64) + q * 16) ^ ((row & 7) << 4));
      na[h][ks] = *(const bf16x8*)((const char*)lT + bo);
    }
  }
  WAIT_LGKM0;                                  // na in regs before overwrite
  #pragma unroll
  for (int h = 0; h < 2; ++h) {
    int row = h * 16 + cl;
    #pragma unroll
    for (int ks = 0; ks < 4; ++ks) {
      int bo = row * 256 + (((ks * 64) + q * 16) ^ ((row & 7) << 4));
      *(bf16x8*)((char*)lT + bo) = pa[h][ks];
    }
  }

  // =========================== PASS 2 (task head) ===========================
  // global step = 84 + t*16 + ks; 84 % 6 == 0; base drifts by 16 % 6 = 4 per t.
  int sb = 0;                                  // (t*16) mod 6
  #pragma unroll 1
  for (int t = 0; t < 7; ++t) {
    f32x4 aZ[2], aR[2], aNa[2], aNb[2];
    #pragma unroll
    for (int h = 0; h < 2; ++h) { aZ[h] = (f32x4)(0.f); aR[h] = (f32x4)(0.f); aNa[h] = (f32x4)(0.f); aNb[h] = (f32x4)(0.f); }
    #pragma unroll
    for (int ks = 0; ks < 16; ks += 2) {
      int s0 = sb + (ks % NSLOT);          if (s0 >= NSLOT) s0 -= NSLOT;
      int s1 = sb + ((ks + 1) % NSLOT);    if (s1 >= NSLOT) s1 -= NSLOT;
      const uint16_t* sp0 = ring + s0 * 1536 + lane * 8;
      const uint16_t* sp1 = ring + s1 * 1536 + lane * 8;
      bf16x8 a0 = *(const bf16x8*)(sp0);
      bf16x8 a1 = *(const bf16x8*)(sp0 + 512);
      bf16x8 a2 = *(const bf16x8*)(sp0 + 1024);
      bf16x8 b0 = *(const bf16x8*)(sp1);
      bf16x8 b1 = *(const bf16x8*)(sp1 + 512);
      bf16x8 b2 = *(const bf16x8*)(sp1 + 1024);
      if (wid < 3) {
        const int k4 = ks + 4, k5 = ks + 5;
        int f4 = (k4 < 16) ? (P2_FRAG + t * 48 + k4 * 3)
               : (t < 6 ? (P2_FRAG + (t + 1) * 48 + (k4 - 16) * 3) : P2_FRAG);   // tail clamp
        int f5 = (k5 < 16) ? (P2_FRAG + t * 48 + k5 * 3)
               : (t < 6 ? (P2_FRAG + (t + 1) * 48 + (k5 - 16) * 3) : P2_FRAG);   // tail clamp
        int s4 = sb + (k4 % NSLOT);        if (s4 >= NSLOT) s4 -= NSLOT;
        int s5 = sb + (k5 % NSLOT);        if (s5 >= NSLOT) s5 -= NSLOT;
        gload(wsl + (size_t)(f4 + wid) * 512, ring + s4 * 1536 + wid * 512);
        gload(wsl + (size_t)(f5 + wid) * 512, ring + s5 * 1536 + wid * 512);
      }
      __builtin_amdgcn_s_setprio(1);
      #pragma unroll
      for (int h = 0; h < 2; ++h) {
        bf16x8 av0 = (ks < 8) ? xa[h][ks] : (ks < 12) ? pa[h][ks - 8] : na[h][ks - 12];
        aZ[h] = MFMA(av0, a0, aZ[h]);
        aR[h] = MFMA(av0, a1, aR[h]);
        if (ks < 8)       aNa[h] = MFMA(av0, a2, aNa[h]);
        else if (ks < 12) aNb[h] = MFMA(av0, a2, aNb[h]);
        else              aNa[h] = MFMA(av0, a2, aNa[h]);
        bf16x8 av1 = (ks + 1 < 8) ? xa[h][ks + 1] : (ks + 1 < 12) ? pa[h][ks + 1 - 8] : na[h][ks + 1 - 12];
        aZ[h] = MFMA(av1, b0, aZ[h]);
        aR[h] = MFMA(av1, b1, aR[h]);
        if (ks + 1 < 8)       aNa[h] = MFMA(av1, b2, aNa[h]);
        else if (ks + 1 < 12) aNb[h] = MFMA(av1, b2, aNb[h]);
        else                  aNa[h] = MFMA(av1, b2, aNa[h]);
      }
      __builtin_amdgcn_s_setprio(0);
      if (wid < 3) WAIT_VM2;
      BAR;
    }
    // elementwise + store (hpv from lT)
    int c = t * 16 + cl;
    bool valid = c < H_DIM;
    #pragma unroll
    for (int h = 0; h < 2; ++h) {
      #pragma unroll
      for (int r = 0; r < 4; ++r) {
        int row = h * 16 + q * 4 + r;
        int bo = row * 256 + ((c * 2) ^ ((row & 7) << 4));
        float hpv = bf2f(*(const uint16_t*)((const char*)lT + bo));
        float z2 = sigmoidf_(aZ[h][r]);
        float r2 = sigmoidf_(aR[h][r]);
        float nm = tanhf_(aNa[h][r] + r2 * aNb[h][r]);
        float hnew = (1.f - z2) * nm + z2 * hpv;
        if (valid) out[(size_t)(rowbase + row) * H_DIM + c] = hnew;
      }
    }
    sb += 4;
    if (sb >= NSLOT) sb -= NSLOT;
  }

  // drain outstanding DMAs (protect reallocated LDS from late landings)
  WAIT_VM0;
}

extern "C" void kernel_launch(void* const* d_in, const int* in_sizes, int n_in,
                              void* d_out, int out_size, void* d_ws, size_t ws_size,
                              hipStream_t stream) {
  const float* x    = (const float*)d_in[0];
  const float* h_p  = (const float*)d_in[1];
  const float* h_s  = (const float*)d_in[2];
  const float* Wi   = (const float*)d_in[3];
  const float* Wh   = (const float*)d_in[4];
  const float* bi   = (const float*)d_in[5];
  const float* bh   = (const float*)d_in[6];
  const float* W_z  = (const float*)d_in[7];
  const float* U_z  = (const float*)d_in[8];
  const float* Us_z = (const float*)d_in[9];
  const float* W_r  = (const float*)d_in[10];
  const float* U_r  = (const float*)d_in[11];
  const float* Us_r = (const float*)d_in[12];
  const float* W_hn = (const float*)d_in[13];
  const float* U_hn = (const float*)d_in[14];
  const float* Us_hn= (const float*)d_in[15];
  uint16_t* ws = (uint16_t*)d_ws;
  float* out = (float*)d_out;

  int rows = in_sizes[0] / D_IN;          // 262144
  prepack_kernel<<<(TOTAL_E + 255) / 256, 256, 0, stream>>>(
      Wi, Wh, W_z, U_z, Us_z, W_r, U_r, Us_r, W_hn, U_hn, Us_hn, bi, bh, ws);
  gru_fused<<<rows / BM, NTHREADS, 0, stream>>>(x, h_p, h_s, ws, out);
}